// Round 1
// baseline (1269.826 us; speedup 1.0000x reference)
//
#include <hip/hip_runtime.h>
#include <hip/hip_bf16.h>

#define T_TOK 2048
#define H_DIM 2048
#define E_NUM 32
#define I_DIM 768
#define TOPK  4

// ---------------- Router: logits, top-4, renorm weights, scatter ----------------
__global__ __launch_bounds__(64) void router_kernel(
    const float* __restrict__ x, const float* __restrict__ gate_w,
    float* __restrict__ logits_out, int* __restrict__ cnt,
    int* __restrict__ tok_list, float* __restrict__ tok_w)
{
    const int t = blockIdx.x;
    const int lane = threadIdx.x;
    __shared__ float xs[H_DIM];
    const float4* __restrict__ xv = (const float4*)(x + (size_t)t * H_DIM);
    float4* xsv = (float4*)xs;
#pragma unroll
    for (int i = 0; i < H_DIM / 4 / 64; ++i) xsv[lane + i * 64] = xv[lane + i * 64];
    __syncthreads();

    const int e = lane & 31;
    const int half = lane >> 5;
    const float4* __restrict__ wv = (const float4*)(gate_w + (size_t)e * H_DIM) + half * (H_DIM / 8);
    const float4* __restrict__ xh = ((const float4*)xs) + half * (H_DIM / 8);
    float acc = 0.f;
#pragma unroll 4
    for (int i = 0; i < H_DIM / 8; ++i) {
        float4 w4 = wv[i], x4 = xh[i];
        acc += w4.x * x4.x + w4.y * x4.y + w4.z * x4.z + w4.w * x4.w;
    }
    acc += __shfl_xor(acc, 32, 64);   // combine the two H-halves
    if (lane < 32) logits_out[(size_t)t * E_NUM + e] = acc;

    // top-4 over lanes 0..31 (values mirrored in upper half; width-32 shuffles)
    float v = acc;
    float topv[TOPK]; int topi[TOPK];
#pragma unroll
    for (int r = 0; r < TOPK; ++r) {
        float bv = v; int bi = e;
#pragma unroll
        for (int off = 16; off >= 1; off >>= 1) {
            float ov = __shfl_xor(bv, off, 32);
            int   oi = __shfl_xor(bi, off, 32);
            if (ov > bv || (ov == bv && oi < bi)) { bv = ov; bi = oi; }  // jax tie-break: lower idx
        }
        topv[r] = bv; topi[r] = bi;
        if (e == bi) v = -1e30f;
    }
    if (lane == 0) {
        float w[TOPK]; float s = 0.f;
#pragma unroll
        for (int r = 0; r < TOPK; ++r) { w[r] = expf(topv[r] - topv[0]); s += w[r]; }
        float inv = 1.f / s;
#pragma unroll
        for (int r = 0; r < TOPK; ++r) {
            int pos = atomicAdd(&cnt[topi[r]], 1);
            tok_list[topi[r] * T_TOK + pos] = t;
            tok_w  [topi[r] * T_TOK + pos] = w[r] * inv;
        }
    }
}

// ---------------- Prefix scan of per-expert counts ----------------
__global__ void scan_kernel(const int* __restrict__ cnt, int* __restrict__ slot_base)
{
    if (threadIdx.x == 0) {
        int s = 0;
        for (int e = 0; e < E_NUM; ++e) { slot_base[e] = s; s += cnt[e]; }
        slot_base[E_NUM] = s;
    }
}

// ---------------- Grouped GEMM: gate_up + silu -> h ----------------
// grid: (I/64 n-tiles, T/64 m-tiles (early-exit), E experts), block 256
__global__ __launch_bounds__(256) void gateup_kernel(
    const float* __restrict__ x, const float* __restrict__ gup_w,
    const int* __restrict__ cnt, const int* __restrict__ slot_base,
    const int* __restrict__ tok_list, float* __restrict__ h_buf)
{
    const int e  = blockIdx.z;
    const int mt = blockIdx.y;
    const int nt = blockIdx.x;
    const int count = cnt[e];
    if (mt * 64 >= count) return;
    const int tid = threadIdx.x;

    __shared__ float As[16][64];
    __shared__ float Bg[16][64];
    __shared__ float Bu[16][64];
    __shared__ int   toks[64];

    if (tid < 64) {
        int m = mt * 64 + tid; if (m >= count) m = count - 1;
        toks[tid] = tok_list[e * T_TOK + m];
    }
    __syncthreads();

    const int lm  = tid & 63;
    const int lk4 = (tid >> 6) << 2;
    const int bk  = tid >> 4;
    const int bn  = (tid & 15) << 2;
    const int ty  = tid >> 4;
    const int tx  = tid & 15;

    const float* __restrict__ arow = x + (size_t)toks[lm] * H_DIM + lk4;
    const float* __restrict__ wb   = gup_w + (size_t)e * H_DIM * (2 * I_DIM)
                                   + (size_t)bk * (2 * I_DIM) + nt * 64 + bn;

    float acc_g[4][4] = {{0.f}};
    float acc_u[4][4] = {{0.f}};

    for (int kk = 0; kk < H_DIM; kk += 16) {
        float4 a4 = *(const float4*)(arow + kk);
        As[lk4 + 0][lm] = a4.x; As[lk4 + 1][lm] = a4.y;
        As[lk4 + 2][lm] = a4.z; As[lk4 + 3][lm] = a4.w;
        float4 bg = *(const float4*)(wb + (size_t)kk * (2 * I_DIM));
        float4 bu = *(const float4*)(wb + (size_t)kk * (2 * I_DIM) + I_DIM);
        *(float4*)&Bg[bk][bn] = bg;
        *(float4*)&Bu[bk][bn] = bu;
        __syncthreads();
#pragma unroll
        for (int k = 0; k < 16; ++k) {
            float4 av = *(const float4*)&As[k][ty * 4];
            float4 gv = *(const float4*)&Bg[k][tx * 4];
            float4 uv = *(const float4*)&Bu[k][tx * 4];
            float a[4] = {av.x, av.y, av.z, av.w};
            float g[4] = {gv.x, gv.y, gv.z, gv.w};
            float u[4] = {uv.x, uv.y, uv.z, uv.w};
#pragma unroll
            for (int i = 0; i < 4; ++i)
#pragma unroll
                for (int j = 0; j < 4; ++j) {
                    acc_g[i][j] = fmaf(a[i], g[j], acc_g[i][j]);
                    acc_u[i][j] = fmaf(a[i], u[j], acc_u[i][j]);
                }
        }
        __syncthreads();
    }

    const int base = slot_base[e];
#pragma unroll
    for (int i = 0; i < 4; ++i) {
        int m = mt * 64 + ty * 4 + i;
        if (m < count) {
            float* hrow = h_buf + (size_t)(base + m) * I_DIM + nt * 64 + tx * 4;
#pragma unroll
            for (int j = 0; j < 4; ++j) {
                float g = acc_g[i][j], u = acc_u[i][j];
                float s = g / (1.f + expf(-g));   // silu
                hrow[j] = u * s;
            }
        }
    }
}

// ---------------- Grouped GEMM: down proj, weighted atomic accumulate ----------------
// grid: (H/64 n-tiles, T/64 m-tiles (early-exit), E experts), block 256
__global__ __launch_bounds__(256) void down_kernel(
    const float* __restrict__ h_buf, const float* __restrict__ down_w,
    const int* __restrict__ cnt, const int* __restrict__ slot_base,
    const int* __restrict__ tok_list, const float* __restrict__ tok_w,
    float* __restrict__ out)
{
    const int e  = blockIdx.z;
    const int mt = blockIdx.y;
    const int nt = blockIdx.x;
    const int count = cnt[e];
    if (mt * 64 >= count) return;
    const int tid = threadIdx.x;

    __shared__ float As[16][64];
    __shared__ float Bs[16][64];
    __shared__ int   toks[64];
    __shared__ float wts[64];

    if (tid < 64) {
        int m = mt * 64 + tid; if (m >= count) m = count - 1;
        toks[tid] = tok_list[e * T_TOK + m];
        wts[tid]  = tok_w [e * T_TOK + m];
    }
    __syncthreads();

    const int lm  = tid & 63;
    const int lk4 = (tid >> 6) << 2;
    const int bk  = tid >> 4;
    const int bn  = (tid & 15) << 2;
    const int ty  = tid >> 4;
    const int tx  = tid & 15;

    const int base = slot_base[e];
    int mrow = mt * 64 + lm; if (mrow >= count) mrow = count - 1;
    const float* __restrict__ arow = h_buf + (size_t)(base + mrow) * I_DIM + lk4;
    const float* __restrict__ wb   = down_w + (size_t)e * I_DIM * H_DIM
                                   + (size_t)bk * H_DIM + nt * 64 + bn;

    float acc[4][4] = {{0.f}};

    for (int kk = 0; kk < I_DIM; kk += 16) {
        float4 a4 = *(const float4*)(arow + kk);
        As[lk4 + 0][lm] = a4.x; As[lk4 + 1][lm] = a4.y;
        As[lk4 + 2][lm] = a4.z; As[lk4 + 3][lm] = a4.w;
        float4 b4 = *(const float4*)(wb + (size_t)kk * H_DIM);
        *(float4*)&Bs[bk][bn] = b4;
        __syncthreads();
#pragma unroll
        for (int k = 0; k < 16; ++k) {
            float4 av = *(const float4*)&As[k][ty * 4];
            float4 bv = *(const float4*)&Bs[k][tx * 4];
            float a[4] = {av.x, av.y, av.z, av.w};
            float b[4] = {bv.x, bv.y, bv.z, bv.w};
#pragma unroll
            for (int i = 0; i < 4; ++i)
#pragma unroll
                for (int j = 0; j < 4; ++j)
                    acc[i][j] = fmaf(a[i], b[j], acc[i][j]);
        }
        __syncthreads();
    }

#pragma unroll
    for (int i = 0; i < 4; ++i) {
        int m = mt * 64 + ty * 4 + i;
        if (m < count) {
            int   tok = toks[ty * 4 + i];
            float w   = wts [ty * 4 + i];
            float* orow = out + (size_t)tok * H_DIM + nt * 64 + tx * 4;
#pragma unroll
            for (int j = 0; j < 4; ++j)
                atomicAdd(&orow[j], w * acc[i][j]);
        }
    }
}

extern "C" void kernel_launch(void* const* d_in, const int* in_sizes, int n_in,
                              void* d_out, int out_size, void* d_ws, size_t ws_size,
                              hipStream_t stream) {
    const float* x      = (const float*)d_in[0];
    const float* gate_w = (const float*)d_in[1];
    const float* gup_w  = (const float*)d_in[2];
    const float* down_w = (const float*)d_in[3];
    float* out    = (float*)d_out;
    float* logits = out + (size_t)T_TOK * H_DIM;

    // workspace carve-up (~25.7 MB total)
    char* w = (char*)d_ws;
    int*   cnt       = (int*)(w);                                 // 32 ints
    int*   slot_base = (int*)(w + 128);                           // 33 ints
    int*   tok_list  = (int*)(w + 1024);                          // E*T ints
    float* tok_w     = (float*)(w + 1024 + (size_t)E_NUM * T_TOK * 4);
    float* h_buf     = (float*)(w + 1024 + (size_t)2 * E_NUM * T_TOK * 4); // 4T x I fp32

    hipMemsetAsync(out, 0, (size_t)T_TOK * H_DIM * sizeof(float), stream);
    hipMemsetAsync(cnt, 0, 128, stream);

    router_kernel<<<T_TOK, 64, 0, stream>>>(x, gate_w, logits, cnt, tok_list, tok_w);
    scan_kernel<<<1, 64, 0, stream>>>(cnt, slot_base);
    gateup_kernel<<<dim3(I_DIM / 64, T_TOK / 64, E_NUM), 256, 0, stream>>>(
        x, gup_w, cnt, slot_base, tok_list, h_buf);
    down_kernel<<<dim3(H_DIM / 64, T_TOK / 64, E_NUM), 256, 0, stream>>>(
        h_buf, down_w, cnt, slot_base, tok_list, tok_w, out);
}

// Round 2
// 653.539 us; speedup vs baseline: 1.9430x; 1.9430x over previous
//
#include <hip/hip_runtime.h>
#include <hip/hip_bf16.h>

#define T_TOK 2048
#define H_DIM 2048
#define E_NUM 32
#define I_DIM 768
#define TOPK  4

typedef __attribute__((ext_vector_type(8))) short bf16x8;
typedef __attribute__((ext_vector_type(4))) float f32x4;

__device__ __forceinline__ unsigned pk2(float a, float b) {
    __hip_bfloat16 ha = __float2bfloat16(a);
    __hip_bfloat16 hb = __float2bfloat16(b);
    unsigned short ua = *(unsigned short*)&ha;
    unsigned short ub = *(unsigned short*)&hb;
    return (unsigned)ua | ((unsigned)ub << 16);
}

__device__ __forceinline__ void gld16(const void* g, void* l) {
    __builtin_amdgcn_global_load_lds(
        (const __attribute__((address_space(1))) void*)g,
        (__attribute__((address_space(3))) void*)l, 16, 0, 0);
}

// ---------------- Router: logits, top-4, renorm weights, scatter ----------------
__global__ __launch_bounds__(64) void router_kernel(
    const float* __restrict__ x, const float* __restrict__ gate_w,
    float* __restrict__ logits_out, int* __restrict__ cnt,
    int* __restrict__ tok_list, float* __restrict__ tok_w)
{
    const int t = blockIdx.x;
    const int lane = threadIdx.x;
    __shared__ float xs[H_DIM];
    const float4* __restrict__ xv = (const float4*)(x + (size_t)t * H_DIM);
    float4* xsv = (float4*)xs;
#pragma unroll
    for (int i = 0; i < H_DIM / 4 / 64; ++i) xsv[lane + i * 64] = xv[lane + i * 64];
    __syncthreads();

    const int e = lane & 31;
    const int half = lane >> 5;
    const float4* __restrict__ wv = (const float4*)(gate_w + (size_t)e * H_DIM) + half * (H_DIM / 8);
    const float4* __restrict__ xh = ((const float4*)xs) + half * (H_DIM / 8);
    float acc = 0.f;
#pragma unroll 4
    for (int i = 0; i < H_DIM / 8; ++i) {
        float4 w4 = wv[i], x4 = xh[i];
        acc += w4.x * x4.x + w4.y * x4.y + w4.z * x4.z + w4.w * x4.w;
    }
    acc += __shfl_xor(acc, 32, 64);
    if (lane < 32) logits_out[(size_t)t * E_NUM + e] = acc;

    float v = acc;
    float topv[TOPK]; int topi[TOPK];
#pragma unroll
    for (int r = 0; r < TOPK; ++r) {
        float bv = v; int bi = e;
#pragma unroll
        for (int off = 16; off >= 1; off >>= 1) {
            float ov = __shfl_xor(bv, off, 32);
            int   oi = __shfl_xor(bi, off, 32);
            if (ov > bv || (ov == bv && oi < bi)) { bv = ov; bi = oi; }
        }
        topv[r] = bv; topi[r] = bi;
        if (e == bi) v = -1e30f;
    }
    if (lane == 0) {
        float w[TOPK]; float s = 0.f;
#pragma unroll
        for (int r = 0; r < TOPK; ++r) { w[r] = expf(topv[r] - topv[0]); s += w[r]; }
        float inv = 1.f / s;
#pragma unroll
        for (int r = 0; r < TOPK; ++r) {
            int pos = atomicAdd(&cnt[topi[r]], 1);
            tok_list[topi[r] * T_TOK + pos] = t;
            tok_w  [topi[r] * T_TOK + pos] = w[r] * inv;
        }
    }
}

__global__ void scan_kernel(const int* __restrict__ cnt, int* __restrict__ slot_base)
{
    if (threadIdx.x == 0) {
        int s = 0;
        for (int e = 0; e < E_NUM; ++e) { slot_base[e] = s; s += cnt[e]; }
        slot_base[E_NUM] = s;
    }
}

// ---------------- Gather tokens per expert, convert x -> bf16 ----------------
// grid (128 chunks, 32 experts), block 256. Each block: 16 slot rows.
__global__ __launch_bounds__(256) void gather_kernel(
    const float* __restrict__ x, const int* __restrict__ cnt,
    const int* __restrict__ slot_base, const int* __restrict__ tok_list,
    unsigned short* __restrict__ xg)
{
    const int e = blockIdx.y;
    const int count = cnt[e];
    const int m0 = blockIdx.x * 16;
    if (m0 >= count) return;
    const int r = threadIdx.x >> 4;
    const int m = m0 + r;
    if (m >= count) return;
    const int tok  = tok_list[e * T_TOK + m];
    const int slot = slot_base[e] + m;
    const float* __restrict__ src = x + (size_t)tok * H_DIM;
    unsigned short* __restrict__ dst = xg + (size_t)slot * H_DIM;
    for (int c = (threadIdx.x & 15) * 4; c < H_DIM; c += 64) {
        float4 v = *(const float4*)(src + c);
        unsigned lo = pk2(v.x, v.y), hi = pk2(v.z, v.w);
        *(unsigned*)(dst + c)     = lo;
        *(unsigned*)(dst + c + 2) = hi;
    }
}

// ---------------- gate_up MFMA grouped GEMM + silu + weight-scale -> h (bf16) ----
// block tile 256(M) x 64(h-cols), BK=32, 8 waves. grid (12, 8, 32).
__global__ __launch_bounds__(512, 4) void gateup_mfma(
    const unsigned short* __restrict__ xg, const float* __restrict__ gup_w,
    const int* __restrict__ cnt, const int* __restrict__ slot_base,
    const float* __restrict__ tok_w, unsigned short* __restrict__ h_buf)
{
    const int e  = blockIdx.z;
    const int mt = blockIdx.y;
    const int nt = blockIdx.x;
    const int count = cnt[e];
    if (mt * 256 >= count) return;
    const int tid  = threadIdx.x;
    const int lane = tid & 63;
    const int w    = tid >> 6;       // 0..7
    const int wm   = w >> 1;         // 0..3 (64-row band)
    const int wn   = w & 1;          // 0..1 (32-col band)
    const int base = slot_base[e];
    const int l16  = lane & 15, lg = lane >> 4;

    __shared__ unsigned short As[4 * 256 * 8];   // [kc][m][8]  16 KB
    __shared__ unsigned short Bg[4 * 64 * 8];    // [kc][n][8]   4 KB
    __shared__ unsigned short Bu[4 * 64 * 8];    //              4 KB
    __shared__ float wls[256];

    if (tid < 256) {
        int m = mt * 256 + tid; if (m >= count) m = count - 1;
        wls[tid] = tok_w[e * T_TOK + m];
    }

    // A staging: wave w -> kc = w>>1, rows q0*64.. and (q0+1)*64..
    const int kc = w >> 1;
    const int q0 = (w & 1) * 2;
    int r0 = mt * 256 + q0 * 64 + lane;       if (r0 >= count) r0 = count - 1;
    int r1 = mt * 256 + (q0 + 1) * 64 + lane; if (r1 >= count) r1 = count - 1;
    const unsigned short* ag0 = xg + (size_t)(base + r0) * H_DIM + kc * 8;
    const unsigned short* ag1 = xg + (size_t)(base + r1) * H_DIM + kc * 8;
    unsigned short* al0 = &As[(kc * 256 + q0 * 64) * 8];
    unsigned short* al1 = &As[(kc * 256 + (q0 + 1) * 64) * 8];

    // B staging: tid<256 gate, >=256 up. k-pair rows, 4 cols each.
    const int half = tid >> 8;
    const int t8   = tid & 255;
    const int kb   = (t8 >> 4) * 2;
    const int n4   = (t8 & 15) * 4;
    const float* __restrict__ bsrc =
        gup_w + ((size_t)e * H_DIM + kb) * (2 * I_DIM) + (size_t)half * I_DIM + nt * 64 + n4;
    unsigned short* bl = half ? Bu : Bg;
    const int bo = ((kb >> 3) * 64 + n4) * 8 + (kb & 7);

    const unsigned short* afp = &As[(lg * 256 + wm * 64 + l16) * 8];
    const unsigned short* bgp = &Bg[(lg * 64 + wn * 32 + l16) * 8];
    const unsigned short* bup = &Bu[(lg * 64 + wn * 32 + l16) * 8];

    f32x4 accg[4][2], accu[4][2];
#pragma unroll
    for (int i = 0; i < 4; ++i)
#pragma unroll
        for (int f = 0; f < 2; ++f) { accg[i][f] = {0.f,0.f,0.f,0.f}; accu[i][f] = {0.f,0.f,0.f,0.f}; }

    float4 rr0 = *(const float4*)bsrc;
    float4 rr1 = *(const float4*)(bsrc + 2 * I_DIM);

    for (int ks = 0; ks < H_DIM / 32; ++ks) {
        __syncthreads();
        gld16(ag0 + ks * 32, al0);
        gld16(ag1 + ks * 32, al1);
        *(unsigned*)&bl[bo +  0] = pk2(rr0.x, rr1.x);
        *(unsigned*)&bl[bo +  8] = pk2(rr0.y, rr1.y);
        *(unsigned*)&bl[bo + 16] = pk2(rr0.z, rr1.z);
        *(unsigned*)&bl[bo + 24] = pk2(rr0.w, rr1.w);
        __syncthreads();
        if (ks + 1 < H_DIM / 32) {   // prefetch next B under this step's MFMAs
            const float* bs = bsrc + (size_t)(ks + 1) * 32 * (2 * I_DIM);
            rr0 = *(const float4*)bs;
            rr1 = *(const float4*)(bs + 2 * I_DIM);
        }
        bf16x8 bg0 = *(const bf16x8*)(bgp);
        bf16x8 bg1 = *(const bf16x8*)(bgp + 128);
        bf16x8 bu0 = *(const bf16x8*)(bup);
        bf16x8 bu1 = *(const bf16x8*)(bup + 128);
#pragma unroll
        for (int i = 0; i < 4; ++i) {
            bf16x8 a = *(const bf16x8*)(afp + i * 128);
            accg[i][0] = __builtin_amdgcn_mfma_f32_16x16x32_bf16(a, bg0, accg[i][0], 0, 0, 0);
            accg[i][1] = __builtin_amdgcn_mfma_f32_16x16x32_bf16(a, bg1, accg[i][1], 0, 0, 0);
            accu[i][0] = __builtin_amdgcn_mfma_f32_16x16x32_bf16(a, bu0, accu[i][0], 0, 0, 0);
            accu[i][1] = __builtin_amdgcn_mfma_f32_16x16x32_bf16(a, bu1, accu[i][1], 0, 0, 0);
        }
    }

#pragma unroll
    for (int i = 0; i < 4; ++i) {
        const int mloc = wm * 64 + i * 16 + lg * 4;
#pragma unroll
        for (int r = 0; r < 4; ++r) {
            const int mrow = mt * 256 + mloc + r;
            if (mrow < count) {
                const float wgt = wls[mloc + r];
#pragma unroll
                for (int f = 0; f < 2; ++f) {
                    const int col = nt * 64 + wn * 32 + f * 16 + l16;
                    float g = accg[i][f][r], u = accu[i][f][r];
                    float sv = g / (1.f + expf(-g));
                    __hip_bfloat16 hb = __float2bfloat16(wgt * u * sv);
                    h_buf[(size_t)(base + mrow) * I_DIM + col] = *(unsigned short*)&hb;
                }
            }
        }
    }
}

// ---------------- down MFMA grouped GEMM -> atomic accumulate into out ----------
// block tile 256(M) x 128(N), BK=32, 8 waves. grid (16, 8, 32).
__global__ __launch_bounds__(512, 4) void down_mfma(
    const unsigned short* __restrict__ h_buf, const float* __restrict__ down_w,
    const int* __restrict__ cnt, const int* __restrict__ slot_base,
    const int* __restrict__ tok_list, float* __restrict__ out)
{
    const int e  = blockIdx.z;
    const int mt = blockIdx.y;
    const int nt = blockIdx.x;
    const int count = cnt[e];
    if (mt * 256 >= count) return;
    const int tid  = threadIdx.x;
    const int lane = tid & 63;
    const int w    = tid >> 6;
    const int wm   = w >> 1;         // 0..3 (64-row band)
    const int wn   = w & 1;          // 0..1 (64-col band)
    const int base = slot_base[e];
    const int l16  = lane & 15, lg = lane >> 4;

    __shared__ unsigned short As[4 * 256 * 8];   // 16 KB
    __shared__ unsigned short Bs[4 * 128 * 8];   //  8 KB
    __shared__ int toks[256];

    if (tid < 256) {
        int m = mt * 256 + tid; if (m >= count) m = count - 1;
        toks[tid] = tok_list[e * T_TOK + m];
    }

    const int kc = w >> 1;
    const int q0 = (w & 1) * 2;
    int r0 = mt * 256 + q0 * 64 + lane;       if (r0 >= count) r0 = count - 1;
    int r1 = mt * 256 + (q0 + 1) * 64 + lane; if (r1 >= count) r1 = count - 1;
    const unsigned short* ag0 = h_buf + (size_t)(base + r0) * I_DIM + kc * 8;
    const unsigned short* ag1 = h_buf + (size_t)(base + r1) * I_DIM + kc * 8;
    unsigned short* al0 = &As[(kc * 256 + q0 * 64) * 8];
    unsigned short* al1 = &As[(kc * 256 + (q0 + 1) * 64) * 8];

    const int kb = (tid >> 5) * 2;           // 0,2,..,30
    const int n4 = (tid & 31) * 4;           // 0..124
    const float* __restrict__ bsrc =
        down_w + ((size_t)e * I_DIM + kb) * H_DIM + nt * 128 + n4;
    const int bo = ((kb >> 3) * 128 + n4) * 8 + (kb & 7);

    const unsigned short* afp = &As[(lg * 256 + wm * 64 + l16) * 8];
    const unsigned short* bfp = &Bs[(lg * 128 + wn * 64 + l16) * 8];

    f32x4 acc[4][4];
#pragma unroll
    for (int i = 0; i < 4; ++i)
#pragma unroll
        for (int f = 0; f < 4; ++f) acc[i][f] = {0.f,0.f,0.f,0.f};

    float4 rr0 = *(const float4*)bsrc;
    float4 rr1 = *(const float4*)(bsrc + H_DIM);

    for (int ks = 0; ks < I_DIM / 32; ++ks) {
        __syncthreads();
        gld16(ag0 + ks * 32, al0);
        gld16(ag1 + ks * 32, al1);
        *(unsigned*)&Bs[bo +  0] = pk2(rr0.x, rr1.x);
        *(unsigned*)&Bs[bo +  8] = pk2(rr0.y, rr1.y);
        *(unsigned*)&Bs[bo + 16] = pk2(rr0.z, rr1.z);
        *(unsigned*)&Bs[bo + 24] = pk2(rr0.w, rr1.w);
        __syncthreads();
        if (ks + 1 < I_DIM / 32) {
            const float* bs2 = bsrc + (size_t)(ks + 1) * 32 * H_DIM;
            rr0 = *(const float4*)bs2;
            rr1 = *(const float4*)(bs2 + H_DIM);
        }
        bf16x8 b0 = *(const bf16x8*)(bfp);
        bf16x8 b1 = *(const bf16x8*)(bfp + 128);
        bf16x8 b2 = *(const bf16x8*)(bfp + 256);
        bf16x8 b3 = *(const bf16x8*)(bfp + 384);
#pragma unroll
        for (int i = 0; i < 4; ++i) {
            bf16x8 a = *(const bf16x8*)(afp + i * 128);
            acc[i][0] = __builtin_amdgcn_mfma_f32_16x16x32_bf16(a, b0, acc[i][0], 0, 0, 0);
            acc[i][1] = __builtin_amdgcn_mfma_f32_16x16x32_bf16(a, b1, acc[i][1], 0, 0, 0);
            acc[i][2] = __builtin_amdgcn_mfma_f32_16x16x32_bf16(a, b2, acc[i][2], 0, 0, 0);
            acc[i][3] = __builtin_amdgcn_mfma_f32_16x16x32_bf16(a, b3, acc[i][3], 0, 0, 0);
        }
    }

#pragma unroll
    for (int i = 0; i < 4; ++i) {
        const int mloc = wm * 64 + i * 16 + lg * 4;
#pragma unroll
        for (int r = 0; r < 4; ++r) {
            const int mrow = mt * 256 + mloc + r;
            if (mrow < count) {
                const int tok = toks[mloc + r];
#pragma unroll
                for (int f = 0; f < 4; ++f) {
                    const int col = nt * 128 + wn * 64 + f * 16 + l16;
                    atomicAdd(&out[(size_t)tok * H_DIM + col], acc[i][f][r]);
                }
            }
        }
    }
}

extern "C" void kernel_launch(void* const* d_in, const int* in_sizes, int n_in,
                              void* d_out, int out_size, void* d_ws, size_t ws_size,
                              hipStream_t stream) {
    const float* x      = (const float*)d_in[0];
    const float* gate_w = (const float*)d_in[1];
    const float* gup_w  = (const float*)d_in[2];
    const float* down_w = (const float*)d_in[3];
    float* out    = (float*)d_out;
    float* logits = out + (size_t)T_TOK * H_DIM;
    (void)logits;

    char* wsp = (char*)d_ws;
    int*   cnt       = (int*)(wsp);
    int*   slot_base = (int*)(wsp + 256);
    int*   tok_list  = (int*)(wsp + 4096);
    float* tok_w     = (float*)(wsp + 4096 + (size_t)E_NUM * T_TOK * 4);
    unsigned short* xg    = (unsigned short*)(wsp + (1u << 20));
    unsigned short* h_buf = (unsigned short*)(wsp + (1u << 20) + (size_t)T_TOK * TOPK * H_DIM * 2);

    hipMemsetAsync(out, 0, (size_t)T_TOK * H_DIM * sizeof(float), stream);
    hipMemsetAsync(cnt, 0, 256, stream);

    router_kernel<<<T_TOK, 64, 0, stream>>>(x, gate_w, out + (size_t)T_TOK * H_DIM,
                                            cnt, tok_list, tok_w);
    scan_kernel<<<1, 64, 0, stream>>>(cnt, slot_base);
    gather_kernel<<<dim3(128, 32), 256, 0, stream>>>(x, cnt, slot_base, tok_list, xg);
    gateup_mfma<<<dim3(I_DIM / 64, 8, E_NUM), 512, 0, stream>>>(
        xg, gup_w, cnt, slot_base, tok_w, h_buf);
    down_mfma<<<dim3(H_DIM / 128, 8, E_NUM), 512, 0, stream>>>(
        h_buf, down_w, cnt, slot_base, tok_list, out);
}

// Round 3
// 618.163 us; speedup vs baseline: 2.0542x; 1.0572x over previous
//
#include <hip/hip_runtime.h>
#include <hip/hip_bf16.h>

#define T_TOK 2048
#define H_DIM 2048
#define E_NUM 32
#define I_DIM 768
#define TOPK  4

typedef __attribute__((ext_vector_type(8))) short bf16x8;
typedef __attribute__((ext_vector_type(4))) float f32x4;

__device__ __forceinline__ unsigned pk2(float a, float b) {
    __hip_bfloat16 ha = __float2bfloat16(a);
    __hip_bfloat16 hb = __float2bfloat16(b);
    unsigned short ua = *(unsigned short*)&ha;
    unsigned short ub = *(unsigned short*)&hb;
    return (unsigned)ua | ((unsigned)ub << 16);
}

__device__ __forceinline__ void gld16(const void* g, void* l) {
    __builtin_amdgcn_global_load_lds(
        (const __attribute__((address_space(1))) void*)g,
        (__attribute__((address_space(3))) void*)l, 16, 0, 0);
}

// ---------------- Router ----------------
__global__ __launch_bounds__(64) void router_kernel(
    const float* __restrict__ x, const float* __restrict__ gate_w,
    float* __restrict__ logits_out, int* __restrict__ cnt,
    int* __restrict__ tok_list, float* __restrict__ tok_w)
{
    const int t = blockIdx.x;
    const int lane = threadIdx.x;
    __shared__ float xs[H_DIM];
    const float4* __restrict__ xv = (const float4*)(x + (size_t)t * H_DIM);
    float4* xsv = (float4*)xs;
#pragma unroll
    for (int i = 0; i < H_DIM / 4 / 64; ++i) xsv[lane + i * 64] = xv[lane + i * 64];
    __syncthreads();

    const int e = lane & 31;
    const int half = lane >> 5;
    const float4* __restrict__ wv = (const float4*)(gate_w + (size_t)e * H_DIM) + half * (H_DIM / 8);
    const float4* __restrict__ xh = ((const float4*)xs) + half * (H_DIM / 8);
    float acc = 0.f;
#pragma unroll 4
    for (int i = 0; i < H_DIM / 8; ++i) {
        float4 w4 = wv[i], x4 = xh[i];
        acc += w4.x * x4.x + w4.y * x4.y + w4.z * x4.z + w4.w * x4.w;
    }
    acc += __shfl_xor(acc, 32, 64);
    if (lane < 32) logits_out[(size_t)t * E_NUM + e] = acc;

    float v = acc;
    float topv[TOPK]; int topi[TOPK];
#pragma unroll
    for (int r = 0; r < TOPK; ++r) {
        float bv = v; int bi = e;
#pragma unroll
        for (int off = 16; off >= 1; off >>= 1) {
            float ov = __shfl_xor(bv, off, 32);
            int   oi = __shfl_xor(bi, off, 32);
            if (ov > bv || (ov == bv && oi < bi)) { bv = ov; bi = oi; }
        }
        topv[r] = bv; topi[r] = bi;
        if (e == bi) v = -1e30f;
    }
    if (lane == 0) {
        float w[TOPK]; float s = 0.f;
#pragma unroll
        for (int r = 0; r < TOPK; ++r) { w[r] = expf(topv[r] - topv[0]); s += w[r]; }
        float inv = 1.f / s;
#pragma unroll
        for (int r = 0; r < TOPK; ++r) {
            int pos = atomicAdd(&cnt[topi[r]], 1);
            tok_list[topi[r] * T_TOK + pos] = t;
            tok_w  [topi[r] * T_TOK + pos] = w[r] * inv;
        }
    }
}

__global__ void scan_kernel(const int* __restrict__ cnt, int* __restrict__ slot_base)
{
    if (threadIdx.x == 0) {
        int s = 0;
        for (int e = 0; e < E_NUM; ++e) { slot_base[e] = s; s += cnt[e]; }
        slot_base[E_NUM] = s;
    }
}

// ---------------- Gather tokens per expert, convert x -> bf16 ----------------
__global__ __launch_bounds__(256) void gather_kernel(
    const float* __restrict__ x, const int* __restrict__ cnt,
    const int* __restrict__ slot_base, const int* __restrict__ tok_list,
    unsigned short* __restrict__ xg)
{
    const int e = blockIdx.y;
    const int count = cnt[e];
    const int m0 = blockIdx.x * 16;
    if (m0 >= count) return;
    const int r = threadIdx.x >> 4;
    const int m = m0 + r;
    if (m >= count) return;
    const int tok  = tok_list[e * T_TOK + m];
    const int slot = slot_base[e] + m;
    const float* __restrict__ src = x + (size_t)tok * H_DIM;
    unsigned short* __restrict__ dst = xg + (size_t)slot * H_DIM;
    for (int c = (threadIdx.x & 15) * 4; c < H_DIM; c += 64) {
        float4 v = *(const float4*)(src + c);
        *(unsigned*)(dst + c)     = pk2(v.x, v.y);
        *(unsigned*)(dst + c + 2) = pk2(v.z, v.w);
    }
}

// ---------------- gate_up MFMA + silu + weight-scale -> h (bf16) ----------------
// block tile 256(M) x 64(h-cols), BK=32, 8 waves, double-buffered. grid (12, 8, 32).
#define NT_GU (H_DIM / 32)
#define ASZ   (4 * 256 * 8)
#define BSZ_GU (4 * 64 * 8)
__global__ __launch_bounds__(512, 4) void gateup_mfma(
    const unsigned short* __restrict__ xg, const float* __restrict__ gup_w,
    const int* __restrict__ cnt, const int* __restrict__ slot_base,
    const float* __restrict__ tok_w, unsigned short* __restrict__ h_buf)
{
    const int e  = blockIdx.z;
    const int mt = blockIdx.y;
    const int nt = blockIdx.x;
    const int count = cnt[e];
    if (mt * 256 >= count) return;
    const int tid  = threadIdx.x;
    const int lane = tid & 63;
    const int w    = tid >> 6;
    const int wm   = w >> 1;
    const int wn   = w & 1;
    const int base = slot_base[e];
    const int l16  = lane & 15, lg = lane >> 4;

    __shared__ unsigned short As[2 * ASZ];
    __shared__ unsigned short Bg[2 * BSZ_GU];
    __shared__ unsigned short Bu[2 * BSZ_GU];
    __shared__ float wls[256];

    if (tid < 256) {
        int m = mt * 256 + tid; if (m >= count) m = count - 1;
        wls[tid] = tok_w[e * T_TOK + m];
    }

    // ---- A staging (global_load_lds): wave -> (kc, two 64-row bands)
    const int kc = w >> 1;
    const int q0 = (w & 1) * 2;
    int r0 = mt * 256 + q0 * 64 + lane;       if (r0 >= count) r0 = count - 1;
    int r1 = mt * 256 + (q0 + 1) * 64 + lane; if (r1 >= count) r1 = count - 1;
    const unsigned short* ag0 = xg + (size_t)(base + r0) * H_DIM + kc * 8;
    const unsigned short* ag1 = xg + (size_t)(base + r1) * H_DIM + kc * 8;
    const int al0 = (kc * 256 + q0 * 64) * 8;
    const int al1 = (kc * 256 + (q0 + 1) * 64) * 8;

    // ---- B staging (reg->convert->LDS), bank-conflict-free mapping:
    // thread: half(g/u), k-pair kb, base col n1; covers cols {n1,n1+16,n1+32,n1+48}
    const int half = tid >> 8;
    const int t8   = tid & 255;
    const int kb   = (t8 >> 4) * 2;
    const int n1   = t8 & 15;
    const int kcb  = kb >> 3;
    const int k8   = kb & 7;
    const float* __restrict__ bsrc =
        gup_w + ((size_t)e * H_DIM + kb) * (2 * I_DIM) + (size_t)half * I_DIM + nt * 64 + n1;
    unsigned short* const blb = half ? Bu : Bg;

    const unsigned short* afp = &As[(lg * 256 + wm * 64 + l16) * 8];
    const unsigned short* bgp = &Bg[(lg * 64 + wn * 32 + l16) * 8];
    const unsigned short* bup = &Bu[(lg * 64 + wn * 32 + l16) * 8];

    f32x4 accg[4][2], accu[4][2];
#pragma unroll
    for (int i = 0; i < 4; ++i)
#pragma unroll
        for (int f = 0; f < 2; ++f) { accg[i][f] = {0.f,0.f,0.f,0.f}; accu[i][f] = {0.f,0.f,0.f,0.f}; }

    float p0[4], p1[4];

    // prologue: stage ks=0 into buffer 0
    gld16(ag0, &As[al0]);
    gld16(ag1, &As[al1]);
#pragma unroll
    for (int j = 0; j < 4; ++j) {
        p0[j] = bsrc[(size_t)j * 16];
        p1[j] = bsrc[(size_t)(2 * I_DIM) + j * 16];
    }
    {
        unsigned short* bw = blb;
#pragma unroll
        for (int j = 0; j < 4; ++j)
            *(unsigned*)&bw[((kcb * 64 + n1 + 16 * j) * 8 + k8)] = pk2(p0[j], p1[j]);
    }

    for (int ks = 0; ks < NT_GU; ++ks) {
        const int cur = ks & 1;
        __syncthreads();   // publishes buf[cur]; reads of buf[cur^1] from ks-1 are done
        if (ks + 1 < NT_GU) {
            gld16(ag0 + (ks + 1) * 32, &As[(cur ^ 1) * ASZ + al0]);
            gld16(ag1 + (ks + 1) * 32, &As[(cur ^ 1) * ASZ + al1]);
            const float* bs = bsrc + (size_t)(ks + 1) * 32 * (2 * I_DIM);
#pragma unroll
            for (int j = 0; j < 4; ++j) {
                p0[j] = bs[(size_t)j * 16];
                p1[j] = bs[(size_t)(2 * I_DIM) + j * 16];
            }
        }
        const unsigned short* af = afp + cur * ASZ;
        const unsigned short* bg = bgp + cur * BSZ_GU;
        const unsigned short* bu = bup + cur * BSZ_GU;
        bf16x8 bg0 = *(const bf16x8*)(bg);
        bf16x8 bg1 = *(const bf16x8*)(bg + 128);
        bf16x8 bu0 = *(const bf16x8*)(bu);
        bf16x8 bu1 = *(const bf16x8*)(bu + 128);
#pragma unroll
        for (int i = 0; i < 4; ++i) {
            bf16x8 a = *(const bf16x8*)(af + i * 128);
            accg[i][0] = __builtin_amdgcn_mfma_f32_16x16x32_bf16(a, bg0, accg[i][0], 0, 0, 0);
            accg[i][1] = __builtin_amdgcn_mfma_f32_16x16x32_bf16(a, bg1, accg[i][1], 0, 0, 0);
            accu[i][0] = __builtin_amdgcn_mfma_f32_16x16x32_bf16(a, bu0, accu[i][0], 0, 0, 0);
            accu[i][1] = __builtin_amdgcn_mfma_f32_16x16x32_bf16(a, bu1, accu[i][1], 0, 0, 0);
        }
        if (ks + 1 < NT_GU) {
            unsigned short* bw = blb + (cur ^ 1) * BSZ_GU;
#pragma unroll
            for (int j = 0; j < 4; ++j)
                *(unsigned*)&bw[((kcb * 64 + n1 + 16 * j) * 8 + k8)] = pk2(p0[j], p1[j]);
        }
    }

#pragma unroll
    for (int i = 0; i < 4; ++i) {
        const int mloc = wm * 64 + i * 16 + lg * 4;
#pragma unroll
        for (int r = 0; r < 4; ++r) {
            const int mrow = mt * 256 + mloc + r;
            if (mrow < count) {
                const float wgt = wls[mloc + r];
#pragma unroll
                for (int f = 0; f < 2; ++f) {
                    const int col = nt * 64 + wn * 32 + f * 16 + l16;
                    float g = accg[i][f][r], u = accu[i][f][r];
                    float sv = g / (1.f + expf(-g));
                    __hip_bfloat16 hb = __float2bfloat16(wgt * u * sv);
                    h_buf[(size_t)(base + mrow) * I_DIM + col] = *(unsigned short*)&hb;
                }
            }
        }
    }
}

// ---------------- down MFMA -> atomic accumulate into out ----------------
// block tile 256(M) x 128(N), BK=32, 8 waves, double-buffered. grid (16, 8, 32).
#define NT_DN (I_DIM / 32)
#define BSZ_DN (4 * 128 * 8)
__global__ __launch_bounds__(512, 4) void down_mfma(
    const unsigned short* __restrict__ h_buf, const float* __restrict__ down_w,
    const int* __restrict__ cnt, const int* __restrict__ slot_base,
    const int* __restrict__ tok_list, float* __restrict__ out)
{
    const int e  = blockIdx.z;
    const int mt = blockIdx.y;
    const int nt = blockIdx.x;
    const int count = cnt[e];
    if (mt * 256 >= count) return;
    const int tid  = threadIdx.x;
    const int lane = tid & 63;
    const int w    = tid >> 6;
    const int wm   = w >> 1;
    const int wn   = w & 1;
    const int base = slot_base[e];
    const int l16  = lane & 15, lg = lane >> 4;

    __shared__ unsigned short As[2 * ASZ];
    __shared__ unsigned short Bs[2 * BSZ_DN];
    __shared__ int toks[256];

    if (tid < 256) {
        int m = mt * 256 + tid; if (m >= count) m = count - 1;
        toks[tid] = tok_list[e * T_TOK + m];
    }

    const int kc = w >> 1;
    const int q0 = (w & 1) * 2;
    int r0 = mt * 256 + q0 * 64 + lane;       if (r0 >= count) r0 = count - 1;
    int r1 = mt * 256 + (q0 + 1) * 64 + lane; if (r1 >= count) r1 = count - 1;
    const unsigned short* ag0 = h_buf + (size_t)(base + r0) * I_DIM + kc * 8;
    const unsigned short* ag1 = h_buf + (size_t)(base + r1) * I_DIM + kc * 8;
    const int al0 = (kc * 256 + q0 * 64) * 8;
    const int al1 = (kc * 256 + (q0 + 1) * 64) * 8;

    // B staging: k-pair kb = (tid>>5)*2, base col n1 = tid&31, cols {n1,+32,+64,+96}
    const int kb  = (tid >> 5) * 2;
    const int n1  = tid & 31;
    const int kcb = kb >> 3;
    const int k8  = kb & 7;
    const float* __restrict__ bsrc =
        down_w + ((size_t)e * I_DIM + kb) * H_DIM + nt * 128 + n1;

    const unsigned short* afp = &As[(lg * 256 + wm * 64 + l16) * 8];
    const unsigned short* bfp = &Bs[(lg * 128 + wn * 64 + l16) * 8];

    f32x4 acc[4][4];
#pragma unroll
    for (int i = 0; i < 4; ++i)
#pragma unroll
        for (int f = 0; f < 4; ++f) acc[i][f] = {0.f,0.f,0.f,0.f};

    float p0[4], p1[4];

    gld16(ag0, &As[al0]);
    gld16(ag1, &As[al1]);
#pragma unroll
    for (int j = 0; j < 4; ++j) {
        p0[j] = bsrc[(size_t)j * 32];
        p1[j] = bsrc[(size_t)H_DIM + j * 32];
    }
    {
        unsigned short* bw = Bs;
#pragma unroll
        for (int j = 0; j < 4; ++j)
            *(unsigned*)&bw[((kcb * 128 + n1 + 32 * j) * 8 + k8)] = pk2(p0[j], p1[j]);
    }

    for (int ks = 0; ks < NT_DN; ++ks) {
        const int cur = ks & 1;
        __syncthreads();
        if (ks + 1 < NT_DN) {
            gld16(ag0 + (ks + 1) * 32, &As[(cur ^ 1) * ASZ + al0]);
            gld16(ag1 + (ks + 1) * 32, &As[(cur ^ 1) * ASZ + al1]);
            const float* bs2 = bsrc + (size_t)(ks + 1) * 32 * H_DIM;
#pragma unroll
            for (int j = 0; j < 4; ++j) {
                p0[j] = bs2[(size_t)j * 32];
                p1[j] = bs2[(size_t)H_DIM + j * 32];
            }
        }
        const unsigned short* af = afp + cur * ASZ;
        const unsigned short* bf = bfp + cur * BSZ_DN;
        bf16x8 b0 = *(const bf16x8*)(bf);
        bf16x8 b1 = *(const bf16x8*)(bf + 128);
        bf16x8 b2 = *(const bf16x8*)(bf + 256);
        bf16x8 b3 = *(const bf16x8*)(bf + 384);
#pragma unroll
        for (int i = 0; i < 4; ++i) {
            bf16x8 a = *(const bf16x8*)(af + i * 128);
            acc[i][0] = __builtin_amdgcn_mfma_f32_16x16x32_bf16(a, b0, acc[i][0], 0, 0, 0);
            acc[i][1] = __builtin_amdgcn_mfma_f32_16x16x32_bf16(a, b1, acc[i][1], 0, 0, 0);
            acc[i][2] = __builtin_amdgcn_mfma_f32_16x16x32_bf16(a, b2, acc[i][2], 0, 0, 0);
            acc[i][3] = __builtin_amdgcn_mfma_f32_16x16x32_bf16(a, b3, acc[i][3], 0, 0, 0);
        }
        if (ks + 1 < NT_DN) {
            unsigned short* bw = Bs + (cur ^ 1) * BSZ_DN;
#pragma unroll
            for (int j = 0; j < 4; ++j)
                *(unsigned*)&bw[((kcb * 128 + n1 + 32 * j) * 8 + k8)] = pk2(p0[j], p1[j]);
        }
    }

#pragma unroll
    for (int i = 0; i < 4; ++i) {
        const int mloc = wm * 64 + i * 16 + lg * 4;
#pragma unroll
        for (int r = 0; r < 4; ++r) {
            const int mrow = mt * 256 + mloc + r;
            if (mrow < count) {
                const int tok = toks[mloc + r];
#pragma unroll
                for (int f = 0; f < 4; ++f) {
                    const int col = nt * 128 + wn * 64 + f * 16 + l16;
                    atomicAdd(&out[(size_t)tok * H_DIM + col], acc[i][f][r]);
                }
            }
        }
    }
}

extern "C" void kernel_launch(void* const* d_in, const int* in_sizes, int n_in,
                              void* d_out, int out_size, void* d_ws, size_t ws_size,
                              hipStream_t stream) {
    const float* x      = (const float*)d_in[0];
    const float* gate_w = (const float*)d_in[1];
    const float* gup_w  = (const float*)d_in[2];
    const float* down_w = (const float*)d_in[3];
    float* out    = (float*)d_out;

    char* wsp = (char*)d_ws;
    int*   cnt       = (int*)(wsp);
    int*   slot_base = (int*)(wsp + 256);
    int*   tok_list  = (int*)(wsp + 4096);
    float* tok_w     = (float*)(wsp + 4096 + (size_t)E_NUM * T_TOK * 4);
    unsigned short* xg    = (unsigned short*)(wsp + (1u << 20));
    unsigned short* h_buf = (unsigned short*)(wsp + (1u << 20) + (size_t)T_TOK * TOPK * H_DIM * 2);

    hipMemsetAsync(out, 0, (size_t)T_TOK * H_DIM * sizeof(float), stream);
    hipMemsetAsync(cnt, 0, 256, stream);

    router_kernel<<<T_TOK, 64, 0, stream>>>(x, gate_w, out + (size_t)T_TOK * H_DIM,
                                            cnt, tok_list, tok_w);
    scan_kernel<<<1, 64, 0, stream>>>(cnt, slot_base);
    gather_kernel<<<dim3(128, 32), 256, 0, stream>>>(x, cnt, slot_base, tok_list, xg);
    gateup_mfma<<<dim3(I_DIM / 64, 8, E_NUM), 512, 0, stream>>>(
        xg, gup_w, cnt, slot_base, tok_w, h_buf);
    down_mfma<<<dim3(H_DIM / 128, 8, E_NUM), 512, 0, stream>>>(
        h_buf, down_w, cnt, slot_base, tok_list, out);
}